// Round 1
// baseline (1916.383 us; speedup 1.0000x reference)
//
#include <hip/hip_runtime.h>
#include <hip/hip_bf16.h>

// Problem constants
static constexpr int B_  = 64;
static constexpr int LT_ = 1024;
static constexpr int LV_ = 576;
static constexpr int E_  = 768;
static constexpr int K_  = 128;

// ---------------------------------------------------------------------------
// Generic batched SGEMM: C = op(A) @ op(B), 64x64 tile, K-step 16, fp32.
// TA: A stored [Kd, M] (compute A^T @ B). TB: B stored [N, Kd] (compute A @ B^T).
// ---------------------------------------------------------------------------
template<bool TA, bool TB>
__global__ __launch_bounds__(256)
void sgemm64(const float* __restrict__ A, const float* __restrict__ B,
             float* __restrict__ C, int M, int N, int Kd,
             long long sA, long long sB, long long sC)
{
    __shared__ float As[16][68];   // As[kk][m], +4 pad keeps float4 alignment
    __shared__ float Bs[16][68];   // Bs[kk][n]

    const float* Ab = A + (long long)blockIdx.z * sA;
    const float* Bb = B + (long long)blockIdx.z * sB;
    float*       Cb = C + (long long)blockIdx.z * sC;

    const int bm = blockIdx.x * 64;
    const int bn = blockIdx.y * 64;
    const int tid = threadIdx.x;
    const int tx = tid & 15, ty = tid >> 4;

    float acc[4][4] = {};

    for (int k0 = 0; k0 < Kd; k0 += 16) {
        if (!TA) {
            // A[M,Kd] row-major: elem (bm+m, k0+kk)
            const int kk = tid & 15, m0 = tid >> 4;
#pragma unroll
            for (int j = 0; j < 4; ++j) {
                const int m = m0 + j * 16;
                As[kk][m] = Ab[(long long)(bm + m) * Kd + k0 + kk];
            }
        } else {
            // A[Kd,M]: elem (k0+kk, bm+m)
            const int m = tid & 63, kk0 = tid >> 6;
#pragma unroll
            for (int j = 0; j < 4; ++j) {
                const int kk = kk0 + j * 4;
                As[kk][m] = Ab[(long long)(k0 + kk) * M + bm + m];
            }
        }
        if (!TB) {
            // B[Kd,N]: elem (k0+kk, bn+n)
            const int n = tid & 63, kk0 = tid >> 6;
#pragma unroll
            for (int j = 0; j < 4; ++j) {
                const int kk = kk0 + j * 4;
                Bs[kk][n] = Bb[(long long)(k0 + kk) * N + bn + n];
            }
        } else {
            // B[N,Kd]: elem (bn+n, k0+kk)
            const int kk = tid & 15, n0 = tid >> 4;
#pragma unroll
            for (int j = 0; j < 4; ++j) {
                const int n = n0 + j * 16;
                Bs[kk][n] = Bb[(long long)(bn + n) * Kd + k0 + kk];
            }
        }
        __syncthreads();

#pragma unroll
        for (int kk = 0; kk < 16; ++kk) {
            const float4 a4 = *(const float4*)&As[kk][ty * 4];
            const float4 b4 = *(const float4*)&Bs[kk][tx * 4];
            const float av[4] = {a4.x, a4.y, a4.z, a4.w};
            const float bv[4] = {b4.x, b4.y, b4.z, b4.w};
#pragma unroll
            for (int i = 0; i < 4; ++i)
#pragma unroll
                for (int j = 0; j < 4; ++j)
                    acc[i][j] += av[i] * bv[j];
        }
        __syncthreads();
    }

#pragma unroll
    for (int i = 0; i < 4; ++i) {
        float4 o;
        o.x = acc[i][0]; o.y = acc[i][1]; o.z = acc[i][2]; o.w = acc[i][3];
        *(float4*)&Cb[(long long)(bm + ty * 4 + i) * N + bn + tx * 4] = o;
    }
}

// ---------------------------------------------------------------------------
// Epilogue: per (batch, side): scores = tanh(base+add) @ wh, softmax, context.
// side 0: V (L=576, src=image), side 1: Q (L=1024, src=text).
// ---------------------------------------------------------------------------
__device__ __forceinline__ float wave_sum(float v) {
#pragma unroll
    for (int off = 32; off; off >>= 1) v += __shfl_down(v, off);
    return v;
}

__global__ __launch_bounds__(256)
void epilogue(const float* __restrict__ text, const float* __restrict__ image,
              const float* __restrict__ wv_v, const float* __restrict__ wqqc,
              const float* __restrict__ wq_q, const float* __restrict__ wvvc,
              const float* __restrict__ w_hv, const float* __restrict__ w_hq,
              float* __restrict__ ctxv, float* __restrict__ ctxq)
{
    const int b = blockIdx.x;
    const bool qside = (blockIdx.y == 1);
    const int L = qside ? LT_ : LV_;
    const float* base = qside ? (wq_q + (size_t)b * LT_ * K_) : (wv_v + (size_t)b * LV_ * K_);
    const float* addb = qside ? (wvvc + (size_t)b * LT_ * K_) : (wqqc + (size_t)b * LV_ * K_);
    const float* wh   = qside ? w_hq : w_hv;
    const float* src  = qside ? (text + (size_t)b * LT_ * E_) : (image + (size_t)b * LV_ * E_);
    float* ctx = (qside ? ctxq : ctxv) + (size_t)b * E_;

    __shared__ float attn[1024];
    __shared__ float red[8];

    const int tid = threadIdx.x, lane = tid & 63, wave = tid >> 6;
    const float wh0 = wh[lane * 2], wh1 = wh[lane * 2 + 1];

    // scores: one wave per row
    for (int y = wave; y < L; y += 4) {
        const float2 a = *(const float2*)&base[(size_t)y * K_ + lane * 2];
        const float2 c = *(const float2*)&addb[(size_t)y * K_ + lane * 2];
        float s = tanhf(a.x + c.x) * wh0 + tanhf(a.y + c.y) * wh1;
        s = wave_sum(s);
        if (lane == 0) attn[y] = s;
    }
    __syncthreads();

    // max
    float m = -1e30f;
    for (int i = tid; i < L; i += 256) m = fmaxf(m, attn[i]);
#pragma unroll
    for (int off = 32; off; off >>= 1) m = fmaxf(m, __shfl_down(m, off));
    if (lane == 0) red[wave] = m;
    __syncthreads();
    m = fmaxf(fmaxf(red[0], red[1]), fmaxf(red[2], red[3]));

    // exp + sum
    float zs = 0.f;
    for (int i = tid; i < L; i += 256) {
        const float e = expf(attn[i] - m);
        attn[i] = e;
        zs += e;
    }
    zs = wave_sum(zs);
    if (lane == 0) red[4 + wave] = zs;
    __syncthreads();
    const float invZ = 1.0f / (red[4] + red[5] + red[6] + red[7]);

    // context: ctx[e] = invZ * sum_y attn[y]*src[y,e]
    float a0 = 0.f, a1 = 0.f, a2 = 0.f;
#pragma unroll 4
    for (int y = 0; y < L; ++y) {
        const float a = attn[y];
        const float* row = src + (size_t)y * E_;
        a0 += a * row[tid];
        a1 += a * row[tid + 256];
        a2 += a * row[tid + 512];
    }
    ctx[tid]       = a0 * invZ;
    ctx[tid + 256] = a1 * invZ;
    ctx[tid + 512] = a2 * invZ;
}

// ---------------------------------------------------------------------------
// Final: out[b,e] = tanh( (ctxv[b]+ctxq[b]) @ w_s )
// ---------------------------------------------------------------------------
__global__ __launch_bounds__(256)
void final_proj(const float* __restrict__ ctxv, const float* __restrict__ ctxq,
                const float* __restrict__ w_s, float* __restrict__ out)
{
    const int b = blockIdx.y;
    const int e = blockIdx.x * 256 + threadIdx.x;
    __shared__ float cs[E_];
    for (int i = threadIdx.x; i < E_; i += 256)
        cs[i] = ctxv[(size_t)b * E_ + i] + ctxq[(size_t)b * E_ + i];
    __syncthreads();
    float acc = 0.f;
#pragma unroll 4
    for (int k = 0; k < E_; ++k)
        acc += cs[k] * w_s[(size_t)k * E_ + e];
    out[(size_t)b * E_ + e] = tanhf(acc);
}

// ---------------------------------------------------------------------------
// Workspace layout (floats)
// ---------------------------------------------------------------------------
static constexpr size_t N_WQQ  = (size_t)B_ * LT_ * K_;   // wq_q
static constexpr size_t N_WVV  = (size_t)B_ * LV_ * K_;   // wv_v
static constexpr size_t N_KE   = (size_t)B_ * K_ * E_;    // G_q / M_q / M_v / P_v
static constexpr size_t N_CTX  = (size_t)B_ * E_;

static constexpr size_t O_WQQ  = 0;
static constexpr size_t O_WVV  = O_WQQ  + N_WQQ;
static constexpr size_t O_GQ   = O_WVV  + N_WVV;
static constexpr size_t O_MQ   = O_GQ   + N_KE;
static constexpr size_t O_MV   = O_MQ   + N_KE;
static constexpr size_t O_PV   = O_MV   + N_KE;
static constexpr size_t O_WQQC = O_PV   + N_KE;   // wqqc [B,LV,K]
static constexpr size_t O_WVVC = O_WQQC + N_WVV;  // wvvc [B,LT,K]
static constexpr size_t O_CTXV = O_WVVC + N_WQQ;
static constexpr size_t O_CTXQ = O_CTXV + N_CTX;

extern "C" void kernel_launch(void* const* d_in, const int* in_sizes, int n_in,
                              void* d_out, int out_size, void* d_ws, size_t ws_size,
                              hipStream_t stream)
{
    const float* text  = (const float*)d_in[0];
    const float* image = (const float*)d_in[1];
    // d_in[2] = text_attention_mask (int64) — unused by the reference math
    const float* w_b  = (const float*)d_in[3];
    const float* w_v  = (const float*)d_in[4];
    const float* w_q  = (const float*)d_in[5];
    const float* w_hv = (const float*)d_in[6];
    const float* w_hq = (const float*)d_in[7];
    const float* w_s  = (const float*)d_in[8];
    float* out = (float*)d_out;

    float* ws = (float*)d_ws;
    float* wq_q = ws + O_WQQ;
    float* wv_v = ws + O_WVV;
    float* G_q  = ws + O_GQ;
    float* M_q  = ws + O_MQ;
    float* M_v  = ws + O_MV;
    float* P_v  = ws + O_PV;
    float* wqqc = ws + O_WQQC;
    float* wvvc = ws + O_WVVC;
    float* ctxv = ws + O_CTXV;
    float* ctxq = ws + O_CTXQ;

    // 1) wq_q = text @ w_q            [B*LT,768]@[768,128]
    hipLaunchKernelGGL((sgemm64<false,false>), dim3((B_*LT_)/64, K_/64, 1), dim3(256), 0, stream,
                       text, w_q, wq_q, B_*LT_, K_, E_, 0, 0, 0);
    // 2) wv_v = image @ w_v           [B*LV,768]@[768,128]
    hipLaunchKernelGGL((sgemm64<false,false>), dim3((B_*LV_)/64, K_/64, 1), dim3(256), 0, stream,
                       image, w_v, wv_v, B_*LV_, K_, E_, 0, 0, 0);
    // 3) G_q[b] = wq_q[b]^T @ text[b]   [128,1024]^T-stored @ [1024,768]
    hipLaunchKernelGGL((sgemm64<true,false>), dim3(K_/64, E_/64, B_), dim3(256), 0, stream,
                       wq_q, text, G_q, K_, E_, LT_,
                       (long long)LT_*K_, (long long)LT_*E_, (long long)K_*E_);
    // 4) M_q[b] = G_q[b] @ w_b          [128,768]@[768,768] (shared B)
    hipLaunchKernelGGL((sgemm64<false,false>), dim3(K_/64, E_/64, B_), dim3(256), 0, stream,
                       G_q, w_b, M_q, K_, E_, E_,
                       (long long)K_*E_, 0LL, (long long)K_*E_);
    // 5) wqqc[b] = image[b] @ M_q[b]^T  [576,768]@[768,128]
    hipLaunchKernelGGL((sgemm64<false,true>), dim3(LV_/64, K_/64, B_), dim3(256), 0, stream,
                       image, M_q, wqqc, LV_, K_, E_,
                       (long long)LV_*E_, (long long)K_*E_, (long long)LV_*K_);
    // 6) M_v[b] = wv_v[b]^T @ image[b]  [128,576]^T-stored @ [576,768]
    hipLaunchKernelGGL((sgemm64<true,false>), dim3(K_/64, E_/64, B_), dim3(256), 0, stream,
                       wv_v, image, M_v, K_, E_, LV_,
                       (long long)LV_*K_, (long long)LV_*E_, (long long)K_*E_);
    // 7) P_v[b] = w_b @ M_v[b]^T        [768,768]@[768,128] (shared A)
    hipLaunchKernelGGL((sgemm64<false,true>), dim3(E_/64, K_/64, B_), dim3(256), 0, stream,
                       w_b, M_v, P_v, E_, K_, E_,
                       0LL, (long long)K_*E_, (long long)E_*K_);
    // 8) wvvc[b] = text[b] @ P_v[b]     [1024,768]@[768,128]
    hipLaunchKernelGGL((sgemm64<false,false>), dim3(LT_/64, K_/64, B_), dim3(256), 0, stream,
                       text, P_v, wvvc, LT_, K_, E_,
                       (long long)LT_*E_, (long long)E_*K_, (long long)LT_*K_);
    // 9) scores + softmax + contexts
    hipLaunchKernelGGL(epilogue, dim3(B_, 2), dim3(256), 0, stream,
                       text, image, wv_v, wqqc, wq_q, wvvc, w_hv, w_hq, ctxv, ctxq);
    // 10) out = tanh((ctxv+ctxq) @ w_s)
    hipLaunchKernelGGL(final_proj, dim3(E_/256, B_), dim3(256), 0, stream,
                       ctxv, ctxq, w_s, out);
}

// Round 2
// 1614.833 us; speedup vs baseline: 1.1867x; 1.1867x over previous
//
#include <hip/hip_runtime.h>

static constexpr int B_  = 64;
static constexpr int LT_ = 1024;
static constexpr int LV_ = 576;
static constexpr int E_  = 768;
static constexpr int K_  = 128;

typedef __attribute__((ext_vector_type(8))) short bf16x8;
typedef __attribute__((ext_vector_type(4))) float f32x4;

// ---------------------------------------------------------------------------
// fp32 -> bf16 split helpers (RNE; inputs are finite, no NaN handling needed)
// ---------------------------------------------------------------------------
__device__ __forceinline__ unsigned short f2bf(float f) {
    unsigned int u = __float_as_uint(f);
    u += 0x7FFFu + ((u >> 16) & 1u);
    return (unsigned short)(u >> 16);
}
__device__ __forceinline__ float bf2f(unsigned short h) {
    return __uint_as_float(((unsigned int)h) << 16);
}

// LDS tile index (in ushorts) for element (row, kk), kk in [0,32).
// 16B-group swizzle: group g=kk>>3 stored at slot g^(row&3). Keeps staging
// writes and ds_read_b128 frag reads bank-conflict-free (row stride 64B).
__device__ __forceinline__ int lds_idx(int row, int kk) {
    return row * 32 + ((((kk >> 3) ^ (row & 3)) << 3) | (kk & 7));
}
__device__ __forceinline__ int lds_idx_grp(int row, int g) {
    return row * 32 + ((g ^ (row & 3)) << 3);
}

// Stage a [128 rows x 32 k] fp32 tile (row-major, leading dim ld) into
// hi/lo bf16 LDS planes. Rows >= Rvalid are zero-filled.
__device__ __forceinline__ void stage_rm(const float* __restrict__ G, int ld,
        int row0, int k0, int Rvalid,
        unsigned short* __restrict__ Sh, unsigned short* __restrict__ Sl, int tid)
{
#pragma unroll
    for (int i = 0; i < 4; ++i) {
        const int f = i * 256 + tid;       // 0..1023
        const int r = f >> 3;              // 0..127
        const int kk = (f & 7) * 4;        // 0,4,...,28
        float4 v = make_float4(0.f, 0.f, 0.f, 0.f);
        if (row0 + r < Rvalid)
            v = *(const float4*)(G + (long long)(row0 + r) * ld + (k0 + kk));
        ushort4 h, l;
        h.x = f2bf(v.x); l.x = f2bf(v.x - bf2f(h.x));
        h.y = f2bf(v.y); l.y = f2bf(v.y - bf2f(h.y));
        h.z = f2bf(v.z); l.z = f2bf(v.z - bf2f(h.z));
        h.w = f2bf(v.w); l.w = f2bf(v.w - bf2f(h.w));
        const int idx = lds_idx(r, kk);
        *(ushort4*)(Sh + idx) = h;
        *(ushort4*)(Sl + idx) = l;
    }
}

// Stage B' where the GLOBAL is column-stored: B'[n,k] = G[k*ld + n]
// (i.e. G is [K rows, N cols] row-major; used for text/image along x).
// N is always 768 here -> no n guard; K always a multiple of 32.
__device__ __forceinline__ void stage_bcol(const float* __restrict__ G, int ld,
        int n0, int k0,
        unsigned short* __restrict__ Sh, unsigned short* __restrict__ Sl, int tid)
{
#pragma unroll
    for (int i = 0; i < 4; ++i) {
        const int f = i * 256 + tid;             // 0..1023
        const int n  = ((f >> 7) << 4) | (f & 15);  // 0..127
        const int kg = (f >> 4) & 7;                // k-group of 4
        float v0 = G[(long long)(k0 + kg * 4 + 0) * ld + n0 + n];
        float v1 = G[(long long)(k0 + kg * 4 + 1) * ld + n0 + n];
        float v2 = G[(long long)(k0 + kg * 4 + 2) * ld + n0 + n];
        float v3 = G[(long long)(k0 + kg * 4 + 3) * ld + n0 + n];
        ushort4 h, l;
        h.x = f2bf(v0); l.x = f2bf(v0 - bf2f(h.x));
        h.y = f2bf(v1); l.y = f2bf(v1 - bf2f(h.y));
        h.z = f2bf(v2); l.z = f2bf(v2 - bf2f(h.z));
        h.w = f2bf(v3); l.w = f2bf(v3 - bf2f(h.w));
        const int idx = lds_idx(n, kg * 4);
        *(ushort4*)(Sh + idx) = h;
        *(ushort4*)(Sl + idx) = l;
    }
}

// ---------------------------------------------------------------------------
// Canonical batched GEMM, emulated fp32 via bf16x3 (hi*hi + hi*lo + lo*hi):
//   C[128, N] = A[128, K] @ B'^T,  B'[N, K]
// BCOL: B' given column-stored as G[K, N] row-major.
// Tile 128x128, 4 waves (2x2), each wave 64x64 via 4x4 frags of 16x16x32.
// ---------------------------------------------------------------------------
template<bool BCOL>
__global__ __launch_bounds__(256, 2)
void gemm_bf16x3(const float* __restrict__ A, const float* __restrict__ Bg,
                 float* __restrict__ C, int N, int K, int ldB,
                 long long sA, long long sB, long long sC)
{
    __shared__ unsigned short lds[4 * 4096];
    unsigned short* Ah = lds;
    unsigned short* Al = lds + 4096;
    unsigned short* Bh = lds + 8192;
    unsigned short* Bl = lds + 12288;

    const int tid  = threadIdx.x;
    const int lane = tid & 63, wid = tid >> 6;
    const int wm = (wid >> 1) * 64, wn = (wid & 1) * 64;
    const int lr = lane & 15, lg = lane >> 4;
    const int n0 = blockIdx.x * 128;
    const long long bz = blockIdx.y;

    A  += bz * sA;
    Bg += bz * sB;
    C  += bz * sC;

    f32x4 acc[4][4];
#pragma unroll
    for (int i = 0; i < 4; ++i)
#pragma unroll
        for (int j = 0; j < 4; ++j)
            acc[i][j] = 0.f;

    for (int k0 = 0; k0 < K; k0 += 32) {
        __syncthreads();   // protect LDS writes vs previous iteration's reads
        stage_rm(A, K, 0, k0, 1 << 30, Ah, Al, tid);
        if (!BCOL) stage_rm(Bg, ldB, n0, k0, N, Bh, Bl, tid);
        else       stage_bcol(Bg, ldB, n0, k0, Bh, Bl, tid);
        __syncthreads();

        bf16x8 a_h[4], a_l[4], b_h[4], b_l[4];
#pragma unroll
        for (int fr = 0; fr < 4; ++fr) {
            const int idx = lds_idx_grp(wm + fr * 16 + lr, lg);
            a_h[fr] = *(const bf16x8*)(Ah + idx);
            a_l[fr] = *(const bf16x8*)(Al + idx);
        }
#pragma unroll
        for (int fc = 0; fc < 4; ++fc) {
            const int idx = lds_idx_grp(wn + fc * 16 + lr, lg);
            b_h[fc] = *(const bf16x8*)(Bh + idx);
            b_l[fc] = *(const bf16x8*)(Bl + idx);
        }
#pragma unroll
        for (int fr = 0; fr < 4; ++fr)
#pragma unroll
            for (int fc = 0; fc < 4; ++fc) {
                acc[fr][fc] = __builtin_amdgcn_mfma_f32_16x16x32_bf16(a_h[fr], b_h[fc], acc[fr][fc], 0, 0, 0);
                acc[fr][fc] = __builtin_amdgcn_mfma_f32_16x16x32_bf16(a_h[fr], b_l[fc], acc[fr][fc], 0, 0, 0);
                acc[fr][fc] = __builtin_amdgcn_mfma_f32_16x16x32_bf16(a_l[fr], b_h[fc], acc[fr][fc], 0, 0, 0);
            }
    }

    // C/D frag: col = lane&15, row = (lane>>4)*4 + reg   [verified mapping]
#pragma unroll
    for (int fc = 0; fc < 4; ++fc) {
        const int colg = n0 + wn + fc * 16 + lr;
        if (colg < N) {
#pragma unroll
            for (int fr = 0; fr < 4; ++fr) {
                const int row0 = wm + fr * 16 + lg * 4;
#pragma unroll
                for (int r = 0; r < 4; ++r)
                    C[(long long)(row0 + r) * N + colg] = acc[fr][fc][r];
            }
        }
    }
}

// ---------------------------------------------------------------------------
// fp32 transpose [R,C] -> [C,R] (for the small weight matrices)
// ---------------------------------------------------------------------------
__global__ __launch_bounds__(256)
void transpose_k(const float* __restrict__ in, float* __restrict__ out, int R, int C)
{
    __shared__ float t[32][33];
    const int bx = blockIdx.x * 32, by = blockIdx.y * 32;
    const int x = threadIdx.x & 31, y = threadIdx.x >> 5;
#pragma unroll
    for (int j = 0; j < 32; j += 8)
        if (by + y + j < R && bx + x < C)
            t[y + j][x] = in[(long long)(by + y + j) * C + bx + x];
    __syncthreads();
#pragma unroll
    for (int j = 0; j < 32; j += 8)
        if (bx + y + j < C && by + x < R)
            out[(long long)(bx + y + j) * R + by + x] = t[x][y + j];
}

// ---------------------------------------------------------------------------
// Scores + softmax. grid (B, 2); side 0 = V (L=576), side 1 = Q (L=1024).
// All tensors K-major [128][L] -> coalesced along y.
// ---------------------------------------------------------------------------
__global__ __launch_bounds__(256)
void scores_k(const float* __restrict__ wv_vT, const float* __restrict__ wqqcT,
              const float* __restrict__ wq_qT, const float* __restrict__ wvvcT,
              const float* __restrict__ w_hv, const float* __restrict__ w_hq,
              float* __restrict__ attnV, float* __restrict__ attnQ)
{
    const int b = blockIdx.x;
    const int side = blockIdx.y;
    const int L = side ? LT_ : LV_;
    const float* bt = side ? wq_qT + (long long)b * (K_ * LT_) : wv_vT + (long long)b * (K_ * LV_);
    const float* at = side ? wvvcT + (long long)b * (K_ * LT_) : wqqcT + (long long)b * (K_ * LV_);
    const float* wh = side ? w_hq : w_hv;
    float* ao = side ? attnQ + (long long)b * LT_ : attnV + (long long)b * LV_;

    __shared__ float sm[1024];
    __shared__ float red[8];
    __shared__ float whs[128];
    const int tid = threadIdx.x, lane = tid & 63, wv = tid >> 6;
    if (tid < 128) whs[tid] = wh[tid];
    __syncthreads();

    for (int y = tid; y < L; y += 256) {
        float s = 0.f;
#pragma unroll 4
        for (int k = 0; k < 128; ++k)
            s += tanhf(bt[(long long)k * L + y] + at[(long long)k * L + y]) * whs[k];
        sm[y] = s;
    }
    __syncthreads();

    float m = -1e30f;
    for (int i = tid; i < L; i += 256) m = fmaxf(m, sm[i]);
#pragma unroll
    for (int off = 32; off; off >>= 1) m = fmaxf(m, __shfl_down(m, off));
    if (lane == 0) red[wv] = m;
    __syncthreads();
    m = fmaxf(fmaxf(red[0], red[1]), fmaxf(red[2], red[3]));

    float zs = 0.f;
    for (int i = tid; i < L; i += 256) {
        const float e = expf(sm[i] - m);
        sm[i] = e;
        zs += e;
    }
#pragma unroll
    for (int off = 32; off; off >>= 1) zs += __shfl_down(zs, off);
    if (lane == 0) red[4 + wv] = zs;
    __syncthreads();
    const float invZ = 1.0f / (red[4] + red[5] + red[6] + red[7]);
    for (int i = tid; i < L; i += 256) ao[i] = sm[i] * invZ;
}

// ---------------------------------------------------------------------------
// Partial contexts. grid (B, 2, 12): z = yc*3 + ec; 256-e chunk per block.
// part[b][side*4+yc][768]
// ---------------------------------------------------------------------------
__global__ __launch_bounds__(256)
void context_k(const float* __restrict__ text, const float* __restrict__ image,
               const float* __restrict__ attnQ, const float* __restrict__ attnV,
               float* __restrict__ part)
{
    const int b = blockIdx.x, side = blockIdx.y;
    const int ec = blockIdx.z % 3, yc = blockIdx.z / 3;
    const int L  = side ? LT_ : LV_;
    const int Lc = side ? (LT_ / 4) : (LV_ / 4);
    const float* src = side ? text + (long long)b * LT_ * E_ : image + (long long)b * LV_ * E_;
    const float* at  = side ? attnQ + (long long)b * LT_ : attnV + (long long)b * LV_;
    const int y0 = yc * Lc, y1 = min(y0 + Lc, L);
    const int e = ec * 256 + threadIdx.x;
    float acc = 0.f;
    for (int y = y0; y < y1; ++y)
        acc += at[y] * src[(long long)y * E_ + e];
    part[(((long long)b * 2 + side) * 4 + yc) * E_ + e] = acc;
}

// ---------------------------------------------------------------------------
// out[b,e] = tanh( sum_k ctx[b,k] * w_s[k,e] ),  ctx = sum of 8 partials
// ---------------------------------------------------------------------------
__global__ __launch_bounds__(256)
void final_k(const float* __restrict__ part, const float* __restrict__ w_s,
             float* __restrict__ out)
{
    const int b = blockIdx.y;
    const int e = blockIdx.x * 256 + threadIdx.x;
    __shared__ float cs[E_];
    for (int i = threadIdx.x; i < E_; i += 256) {
        float s = 0.f;
#pragma unroll
        for (int j = 0; j < 8; ++j) s += part[((long long)b * 8 + j) * E_ + i];
        cs[i] = s;
    }
    __syncthreads();
    float acc = 0.f;
#pragma unroll 4
    for (int k = 0; k < E_; ++k)
        acc += cs[k] * w_s[(long long)k * E_ + e];
    out[(long long)b * E_ + e] = tanhf(acc);
}

// ---------------------------------------------------------------------------
// Workspace layout (fp32 elements)
// ---------------------------------------------------------------------------
static constexpr long long N_T  = (long long)K_ * LT_;        // 131072
static constexpr long long N_V  = (long long)K_ * LV_;        // 73728
static constexpr long long N_KE = (long long)K_ * E_;         // 98304

static constexpr long long O_WQQT  = 0;                        // [B][128][1024]
static constexpr long long O_WVVT  = O_WQQT + B_ * N_T;        // [B][128][576]
static constexpr long long O_GQ    = O_WVVT + B_ * N_V;        // [B][128][768]
static constexpr long long O_MQ    = O_GQ   + B_ * N_KE;
static constexpr long long O_MV    = O_MQ   + B_ * N_KE;
static constexpr long long O_PVT   = O_MV   + B_ * N_KE;
static constexpr long long O_WQQCT = O_PVT  + B_ * N_KE;       // [B][128][576]
static constexpr long long O_WVVCT = O_GQ;  // alias: G_q/M_q dead by GEMM8
static constexpr long long O_WQT   = O_WQQCT + B_ * N_V;       // [128][768]
static constexpr long long O_WVT   = O_WQT + N_KE;
static constexpr long long O_WBT   = O_WVT + N_KE;             // [768][768]
static constexpr long long O_ATTNV = O_WBT + (long long)E_ * E_;
static constexpr long long O_ATTNQ = O_ATTNV + (long long)B_ * LV_;
static constexpr long long O_PART  = O_ATTNQ + (long long)B_ * LT_;
// end = O_PART + 64*8*768 = 44,273,664 floats = 177.1 MB

extern "C" void kernel_launch(void* const* d_in, const int* in_sizes, int n_in,
                              void* d_out, int out_size, void* d_ws, size_t ws_size,
                              hipStream_t stream)
{
    const float* text  = (const float*)d_in[0];
    const float* image = (const float*)d_in[1];
    // d_in[2] = text_attention_mask (all ones; unused by the math)
    const float* w_b  = (const float*)d_in[3];
    const float* w_v  = (const float*)d_in[4];
    const float* w_q  = (const float*)d_in[5];
    const float* w_hv = (const float*)d_in[6];
    const float* w_hq = (const float*)d_in[7];
    const float* w_s  = (const float*)d_in[8];
    float* out = (float*)d_out;

    float* ws = (float*)d_ws;
    float* wq_qT  = ws + O_WQQT;
    float* wv_vT  = ws + O_WVVT;
    float* G_q    = ws + O_GQ;
    float* M_q    = ws + O_MQ;
    float* M_v    = ws + O_MV;
    float* P_vT   = ws + O_PVT;
    float* wqqcT  = ws + O_WQQCT;
    float* wvvcT  = ws + O_WVVCT;
    float* w_qT   = ws + O_WQT;
    float* w_vT   = ws + O_WVT;
    float* w_bT   = ws + O_WBT;
    float* attnV  = ws + O_ATTNV;
    float* attnQ  = ws + O_ATTNQ;
    float* part   = ws + O_PART;

    const long long sTXT = (long long)LT_ * E_;   // 786432
    const long long sIMG = (long long)LV_ * E_;   // 442368

    // Pre-transpose small weights
    hipLaunchKernelGGL(transpose_k, dim3(4, 24), dim3(256), 0, stream, w_q, w_qT, E_, K_);
    hipLaunchKernelGGL(transpose_k, dim3(4, 24), dim3(256), 0, stream, w_v, w_vT, E_, K_);
    hipLaunchKernelGGL(transpose_k, dim3(24, 24), dim3(256), 0, stream, w_b, w_bT, E_, E_);

    // G1: wq_qT[b] = w_qT @ text[b]^T       [128,1024]
    hipLaunchKernelGGL((gemm_bf16x3<false>), dim3(8, B_), dim3(256), 0, stream,
                       w_qT, text, wq_qT, LT_, E_, E_, 0LL, sTXT, N_T);
    // G2: wv_vT[b] = w_vT @ image[b]^T      [128,576]
    hipLaunchKernelGGL((gemm_bf16x3<false>), dim3(5, B_), dim3(256), 0, stream,
                       w_vT, image, wv_vT, LV_, E_, E_, 0LL, sIMG, N_V);
    // G3: G_q[b] = wq_qT[b] @ text[b]       [128,768], K=1024, B column-stored
    hipLaunchKernelGGL((gemm_bf16x3<true>), dim3(6, B_), dim3(256), 0, stream,
                       wq_qT, text, G_q, E_, LT_, E_, N_T, sTXT, N_KE);
    // G4: M_q[b] = G_q[b] @ w_b             [128,768]  (B' = w_bT)
    hipLaunchKernelGGL((gemm_bf16x3<false>), dim3(6, B_), dim3(256), 0, stream,
                       G_q, w_bT, M_q, E_, E_, E_, N_KE, 0LL, N_KE);
    // G5: wqqcT[b] = M_q[b] @ image[b]^T    [128,576]
    hipLaunchKernelGGL((gemm_bf16x3<false>), dim3(5, B_), dim3(256), 0, stream,
                       M_q, image, wqqcT, LV_, E_, E_, N_KE, sIMG, N_V);
    // G6: M_v[b] = wv_vT[b] @ image[b]      [128,768], K=576, B column-stored
    hipLaunchKernelGGL((gemm_bf16x3<true>), dim3(6, B_), dim3(256), 0, stream,
                       wv_vT, image, M_v, E_, LV_, E_, N_V, sIMG, N_KE);
    // G7: P_vT[b] = M_v[b] @ w_b^T          [128,768]  (B' = w_b row-major)
    hipLaunchKernelGGL((gemm_bf16x3<false>), dim3(6, B_), dim3(256), 0, stream,
                       M_v, w_b, P_vT, E_, E_, E_, N_KE, 0LL, N_KE);
    // G8: wvvcT[b] = P_vT[b] @ text[b]^T    [128,1024]
    hipLaunchKernelGGL((gemm_bf16x3<false>), dim3(8, B_), dim3(256), 0, stream,
                       P_vT, text, wvvcT, LT_, E_, E_, N_KE, sTXT, N_T);

    // scores + softmax
    hipLaunchKernelGGL(scores_k, dim3(B_, 2), dim3(256), 0, stream,
                       wv_vT, wqqcT, wq_qT, wvvcT, w_hv, w_hq, attnV, attnQ);
    // partial contexts
    hipLaunchKernelGGL(context_k, dim3(B_, 2, 12), dim3(256), 0, stream,
                       text, image, attnQ, attnV, part);
    // final projection
    hipLaunchKernelGGL(final_k, dim3(3, B_), dim3(256), 0, stream,
                       part, w_s, out);
}

// Round 3
// 1072.408 us; speedup vs baseline: 1.7870x; 1.5058x over previous
//
#include <hip/hip_runtime.h>

static constexpr int B_  = 64;
static constexpr int LT_ = 1024;
static constexpr int LV_ = 576;
static constexpr int E_  = 768;
static constexpr int K_  = 128;

typedef __attribute__((ext_vector_type(8))) short bf16x8;
typedef __attribute__((ext_vector_type(4))) float f32x4;

// ---------------------------------------------------------------------------
// fp32 <-> bf16 split helpers (RNE)
// ---------------------------------------------------------------------------
__device__ __forceinline__ unsigned short f2bf(float f) {
    unsigned int u = __float_as_uint(f);
    u += 0x7FFFu + ((u >> 16) & 1u);
    return (unsigned short)(u >> 16);
}
__device__ __forceinline__ float bf2f(unsigned short h) {
    return __uint_as_float(((unsigned int)h) << 16);
}
__device__ __forceinline__ void split4(float4 v, ushort4& h, ushort4& l) {
    h.x = f2bf(v.x); l.x = f2bf(v.x - bf2f(h.x));
    h.y = f2bf(v.y); l.y = f2bf(v.y - bf2f(h.y));
    h.z = f2bf(v.z); l.z = f2bf(v.z - bf2f(h.z));
    h.w = f2bf(v.w); l.w = f2bf(v.w - bf2f(h.w));
}

// granule (8 bf16 = 16B) XOR swizzle within a [rows][64]-bf16 LDS tile:
// keeps both staging writes and ds_read_b128 fragment reads at the free
// 2-way bank level (rows stride 128B -> same banks without it).
__device__ __forceinline__ int swz8(int row, int g) { return g ^ (row & 7); }

enum { SB_PLANE = 0, SB_F32ROW = 1, SB_F32COL = 2 };

// ---------------------------------------------------------------------------
// Canonical batched GEMM, fp32 emulated via bf16x3 (hh + hl + lh):
//   C[128, N] = A[128, K] @ B'^T, B'[N, K]
// A always hi/lo bf16 planes (row-major [128][K]).
// SB_PLANE : B' hi/lo planes [N][K]
// SB_F32ROW: B' fp32 row-major [N][ldB]   (text/image native)
// SB_F32COL: B' fp32 col-stored: B'[n,k] = G[k*ldB + n]  (text/image transposed)
// Tile 128x64, BK=64, 4 waves (2x2), wave-tile 64x32 (4x2 frags of 16x16x32).
// C written as hi/lo bf16 planes.
// ---------------------------------------------------------------------------
template<int SB>
__global__ __launch_bounds__(256, (SB == SB_F32COL) ? 2 : 3)
void gemm128x64(const unsigned short* __restrict__ Ah, const unsigned short* __restrict__ Al,
                const void* __restrict__ Bp0, const void* __restrict__ Bp1,
                unsigned short* __restrict__ Ch, unsigned short* __restrict__ Cl,
                int N, int K, int ldB,
                long long sA, long long sB, long long sC)
{
    __shared__ unsigned short lAh[128 * 64], lAl[128 * 64];
    __shared__ unsigned short lBh[64 * 64],  lBl[64 * 64];
    constexpr int SCRN = (SB == SB_F32COL) ? 64 * 68 : 4;
    __shared__ float scr[SCRN];

    const int tid = threadIdx.x, lane = tid & 63, wid = tid >> 6;
    const int wm = (wid >> 1) * 64, wn = (wid & 1) * 32;
    const int lr = lane & 15, lg = lane >> 4;
    const int bn = blockIdx.x * 64;
    const long long bz = blockIdx.y;

    Ah += bz * sA;  Al += bz * sA;
    const unsigned short* Bhg = (SB == SB_PLANE) ? (const unsigned short*)Bp0 + bz * sB : nullptr;
    const unsigned short* Blg = (SB == SB_PLANE) ? (const unsigned short*)Bp1 + bz * sB : nullptr;
    const float* Bf = (SB != SB_PLANE) ? (const float*)Bp0 + bz * sB : nullptr;
    Ch += bz * sC;  Cl += bz * sC;

    f32x4 acc[4][2];
#pragma unroll
    for (int i = 0; i < 4; ++i)
#pragma unroll
        for (int j = 0; j < 2; ++j) acc[i][j] = 0.f;

    for (int k0 = 0; k0 < K; k0 += 64) {
        __syncthreads();
        // ---- A staging: pure 16B copies from planes
#pragma unroll
        for (int i = 0; i < 4; ++i) {
            const int slot = tid + 256 * i;         // 0..1023
            const int row = slot >> 3, g = slot & 7;
            const long long src = (long long)row * K + k0 + g * 8;
            const int dst = row * 64 + swz8(row, g) * 8;
            *(uint4*)&lAh[dst] = *(const uint4*)(Ah + src);
            *(uint4*)&lAl[dst] = *(const uint4*)(Al + src);
        }
        // ---- B staging
        if constexpr (SB == SB_PLANE) {
#pragma unroll
            for (int i = 0; i < 2; ++i) {
                const int slot = tid + 256 * i;     // 0..511
                const int row = slot >> 3, g = slot & 7;
                const long long src = (long long)(bn + row) * ldB + k0 + g * 8;
                const int dst = row * 64 + swz8(row, g) * 8;
                *(uint4*)&lBh[dst] = *(const uint4*)(Bhg + src);
                *(uint4*)&lBl[dst] = *(const uint4*)(Blg + src);
            }
        } else if constexpr (SB == SB_F32ROW) {
#pragma unroll
            for (int i = 0; i < 4; ++i) {
                const int f = tid + 256 * i;        // 0..1023
                const int row = f >> 4, c4 = (f & 15) * 4;
                const float4 v = *(const float4*)(Bf + (long long)(bn + row) * ldB + k0 + c4);
                ushort4 h, l; split4(v, h, l);
                const int dst = row * 64 + swz8(row, c4 >> 3) * 8 + (c4 & 7);
                *(ushort4*)&lBh[dst] = h;
                *(ushort4*)&lBl[dst] = l;
            }
        } else { // SB_F32COL: coalesced k-row reads -> padded scratch -> transpose
#pragma unroll
            for (int i = 0; i < 4; ++i) {
                const int f = tid + 256 * i;
                const int k = f >> 4, n4 = (f & 15) * 4;
                const float4 v = *(const float4*)(Bf + (long long)(k0 + k) * ldB + bn + n4);
                *(float4*)&scr[k * 68 + n4] = v;
            }
            __syncthreads();
#pragma unroll
            for (int i = 0; i < 4; ++i) {
                const int s = tid + 256 * i;
                const int n = s >> 4, kc = (s & 15) * 4;
                float4 v;
                v.x = scr[(kc + 0) * 68 + n];
                v.y = scr[(kc + 1) * 68 + n];
                v.z = scr[(kc + 2) * 68 + n];
                v.w = scr[(kc + 3) * 68 + n];
                ushort4 h, l; split4(v, h, l);
                const int dst = n * 64 + swz8(n, kc >> 3) * 8 + (kc & 7);
                *(ushort4*)&lBh[dst] = h;
                *(ushort4*)&lBl[dst] = l;
            }
        }
        __syncthreads();

        // ---- fragments + MFMA
#pragma unroll
        for (int ksl = 0; ksl < 2; ++ksl) {
            bf16x8 ah[4], al[4], bh[2], bl[2];
#pragma unroll
            for (int fr = 0; fr < 4; ++fr) {
                const int row = wm + fr * 16 + lr;
                const int idx = row * 64 + swz8(row, ksl * 4 + lg) * 8;
                ah[fr] = *(const bf16x8*)&lAh[idx];
                al[fr] = *(const bf16x8*)&lAl[idx];
            }
#pragma unroll
            for (int fc = 0; fc < 2; ++fc) {
                const int row = wn + fc * 16 + lr;
                const int idx = row * 64 + swz8(row, ksl * 4 + lg) * 8;
                bh[fc] = *(const bf16x8*)&lBh[idx];
                bl[fc] = *(const bf16x8*)&lBl[idx];
            }
#pragma unroll
            for (int fr = 0; fr < 4; ++fr)
#pragma unroll
                for (int fc = 0; fc < 2; ++fc) {
                    acc[fr][fc] = __builtin_amdgcn_mfma_f32_16x16x32_bf16(ah[fr], bh[fc], acc[fr][fc], 0, 0, 0);
                    acc[fr][fc] = __builtin_amdgcn_mfma_f32_16x16x32_bf16(ah[fr], bl[fc], acc[fr][fc], 0, 0, 0);
                    acc[fr][fc] = __builtin_amdgcn_mfma_f32_16x16x32_bf16(al[fr], bh[fc], acc[fr][fc], 0, 0, 0);
                }
        }
    }

    // ---- epilogue: split acc -> hi/lo planes (C/D: col=lane&15, row=(lane>>4)*4+r)
#pragma unroll
    for (int fc = 0; fc < 2; ++fc) {
        const int col = bn + wn + fc * 16 + lr;
#pragma unroll
        for (int fr = 0; fr < 4; ++fr) {
            const int row0 = wm + fr * 16 + lg * 4;
#pragma unroll
            for (int r = 0; r < 4; ++r) {
                const float v = acc[fr][fc][r];
                const unsigned short h = f2bf(v);
                const unsigned short l = f2bf(v - bf2f(h));
                Ch[(long long)(row0 + r) * N + col] = h;
                Cl[(long long)(row0 + r) * N + col] = l;
            }
        }
    }
}

// ---------------------------------------------------------------------------
// Weight split(+transpose): in fp32 [R][C] -> T planes [C][R]; optional native.
// Tiny tensors; simplicity over speed.
// ---------------------------------------------------------------------------
__global__ __launch_bounds__(256)
void wsplit_k(const float* __restrict__ in,
              unsigned short* __restrict__ th, unsigned short* __restrict__ tl,
              unsigned short* __restrict__ nh, unsigned short* __restrict__ nl,
              int R, int C)
{
    const long long tot = (long long)R * C;
    for (long long i = blockIdx.x * 256 + threadIdx.x; i < tot; i += (long long)gridDim.x * 256) {
        const int r = (int)(i / C), c = (int)(i % C);
        const float v = in[i];
        const unsigned short h = f2bf(v);
        const unsigned short l = f2bf(v - bf2f(h));
        th[(long long)c * R + r] = h;
        tl[(long long)c * R + r] = l;
        if (nh) { nh[i] = h; nl[i] = l; }
    }
}

// ---------------------------------------------------------------------------
// Partial scores: grid (B, 2, 4). side 0 = V (L=576, chunk 144),
// side 1 = Q (L=1024, chunk 256). One y per thread.
// ---------------------------------------------------------------------------
__global__ __launch_bounds__(256)
void scores_part(const unsigned short* __restrict__ qh, const unsigned short* __restrict__ ql,
                 const unsigned short* __restrict__ vqh, const unsigned short* __restrict__ vql,
                 const unsigned short* __restrict__ vh, const unsigned short* __restrict__ vl,
                 const unsigned short* __restrict__ qvh, const unsigned short* __restrict__ qvl,
                 const float* __restrict__ w_hv, const float* __restrict__ w_hq,
                 float* __restrict__ rawV, float* __restrict__ rawQ)
{
    const int b = blockIdx.x, side = blockIdx.y, z = blockIdx.z;
    const int tid = threadIdx.x;
    __shared__ float wh[128];
    if (tid < 128) wh[tid] = side ? w_hq[tid] : w_hv[tid];
    __syncthreads();

    const int L = side ? LT_ : LV_;
    const int chunk = side ? 256 : 144;
    if (tid >= chunk) return;
    const int y = z * chunk + tid;

    const unsigned short* Bh = side ? qh  + (long long)b * (K_ * LT_) : vh  + (long long)b * (K_ * LV_);
    const unsigned short* Bl = side ? ql  + (long long)b * (K_ * LT_) : vl  + (long long)b * (K_ * LV_);
    const unsigned short* Ah = side ? vqh + (long long)b * (K_ * LT_) : qvh + (long long)b * (K_ * LV_);
    const unsigned short* Al = side ? vql + (long long)b * (K_ * LT_) : qvl + (long long)b * (K_ * LV_);

    float s = 0.f;
#pragma unroll 4
    for (int k = 0; k < 128; ++k) {
        const long long o = (long long)k * L + y;
        const float bv = bf2f(Bh[o]) + bf2f(Bl[o]);
        const float av = bf2f(Ah[o]) + bf2f(Al[o]);
        s += tanhf(bv + av) * wh[k];
    }
    (side ? rawQ + (long long)b * LT_ : rawV + (long long)b * LV_)[y] = s;
}

// ---------------------------------------------------------------------------
// Softmax in place over raw scores. grid (B, 2).
// ---------------------------------------------------------------------------
__global__ __launch_bounds__(256)
void softmax_k(float* __restrict__ rawV, float* __restrict__ rawQ)
{
    const int b = blockIdx.x, side = blockIdx.y;
    const int L = side ? LT_ : LV_;
    float* a = (side ? rawQ + (long long)b * LT_ : rawV + (long long)b * LV_);

    __shared__ float sm[1024];
    __shared__ float red[8];
    const int tid = threadIdx.x, lane = tid & 63, wv = tid >> 6;

    for (int i = tid; i < L; i += 256) sm[i] = a[i];
    __syncthreads();

    float m = -1e30f;
    for (int i = tid; i < L; i += 256) m = fmaxf(m, sm[i]);
#pragma unroll
    for (int off = 32; off; off >>= 1) m = fmaxf(m, __shfl_down(m, off));
    if (lane == 0) red[wv] = m;
    __syncthreads();
    m = fmaxf(fmaxf(red[0], red[1]), fmaxf(red[2], red[3]));

    float zs = 0.f;
    for (int i = tid; i < L; i += 256) {
        const float e = expf(sm[i] - m);
        sm[i] = e;
        zs += e;
    }
#pragma unroll
    for (int off = 32; off; off >>= 1) zs += __shfl_down(zs, off);
    if (lane == 0) red[4 + wv] = zs;
    __syncthreads();
    const float invZ = 1.0f / (red[4] + red[5] + red[6] + red[7]);
    for (int i = tid; i < L; i += 256) a[i] = sm[i] * invZ;
}

// ---------------------------------------------------------------------------
// Partial contexts. grid (B, 2, 12): z = yc*3 + ec. part[b][side*4+yc][768]
// ---------------------------------------------------------------------------
__global__ __launch_bounds__(256)
void context_k(const float* __restrict__ text, const float* __restrict__ image,
               const float* __restrict__ attnQ, const float* __restrict__ attnV,
               float* __restrict__ part)
{
    const int b = blockIdx.x, side = blockIdx.y;
    const int ec = blockIdx.z % 3, yc = blockIdx.z / 3;
    const int L  = side ? LT_ : LV_;
    const int Lc = side ? (LT_ / 4) : (LV_ / 4);
    const float* src = side ? text + (long long)b * LT_ * E_ : image + (long long)b * LV_ * E_;
    const float* at  = side ? attnQ + (long long)b * LT_ : attnV + (long long)b * LV_;
    const int y0 = yc * Lc, y1 = y0 + Lc;
    const int e = ec * 256 + threadIdx.x;
    float acc = 0.f;
    for (int y = y0; y < y1; ++y)
        acc += at[y] * src[(long long)y * E_ + e];
    part[(((long long)b * 2 + side) * 4 + yc) * E_ + e] = acc;
}

__global__ __launch_bounds__(256)
void final_k(const float* __restrict__ part, const float* __restrict__ w_s,
             float* __restrict__ out)
{
    const int b = blockIdx.y;
    const int e = blockIdx.x * 256 + threadIdx.x;
    __shared__ float cs[E_];
    for (int i = threadIdx.x; i < E_; i += 256) {
        float s = 0.f;
#pragma unroll
        for (int j = 0; j < 8; ++j) s += part[((long long)b * 8 + j) * E_ + i];
        cs[i] = s;
    }
    __syncthreads();
    float acc = 0.f;
#pragma unroll 4
    for (int k = 0; k < E_; ++k)
        acc += cs[k] * w_s[(long long)k * E_ + e];
    out[(long long)b * E_ + e] = tanhf(acc);
}

// ---------------------------------------------------------------------------
// Workspace layout (byte offsets; all 256B-aligned)
// ---------------------------------------------------------------------------
static constexpr long long P_T  = (long long)B_ * K_ * LT_ * 2;  // 16,777,216 B
static constexpr long long P_V  = (long long)B_ * K_ * LV_ * 2;  //  9,437,184 B
static constexpr long long P_KE = (long long)B_ * K_ * E_  * 2;  // 12,582,912 B
static constexpr long long W_KE = (long long)K_ * E_ * 2;        //    196,608 B
static constexpr long long W_EE = (long long)E_ * E_ * 2;        //  1,179,648 B

static constexpr long long O_WQQT_H = 0;
static constexpr long long O_WQQT_L = O_WQQT_H + P_T;
static constexpr long long O_WVVT_H = O_WQQT_L + P_T;
static constexpr long long O_WVVT_L = O_WVVT_H + P_V;
static constexpr long long O_GQ_H   = O_WVVT_L + P_V;
static constexpr long long O_GQ_L   = O_GQ_H + P_KE;
static constexpr long long O_MQ_H   = O_GQ_L + P_KE;
static constexpr long long O_MQ_L   = O_MQ_H + P_KE;
static constexpr long long O_MV_H   = O_MQ_L + P_KE;
static constexpr long long O_MV_L   = O_MV_H + P_KE;
static constexpr long long O_PV_H   = O_MV_L + P_KE;
static constexpr long long O_PV_L   = O_PV_H + P_KE;
static constexpr long long O_QQC_H  = O_PV_L + P_KE;
static constexpr long long O_QQC_L  = O_QQC_H + P_V;
static constexpr long long O_VVC_H  = O_QQC_L + P_V;
static constexpr long long O_VVC_L  = O_VVC_H + P_T;
static constexpr long long O_WQT_H  = O_VVC_L + P_T;
static constexpr long long O_WQT_L  = O_WQT_H + W_KE;
static constexpr long long O_WVT_H  = O_WQT_L + W_KE;
static constexpr long long O_WVT_L  = O_WVT_H + W_KE;
static constexpr long long O_WBT_H  = O_WVT_L + W_KE;
static constexpr long long O_WBT_L  = O_WBT_H + W_EE;
static constexpr long long O_WBN_H  = O_WBT_L + W_EE;
static constexpr long long O_WBN_L  = O_WBN_H + W_EE;
static constexpr long long O_RAWV   = O_WBN_L + W_EE;
static constexpr long long O_RAWQ   = O_RAWV + (long long)B_ * LV_ * 4;
static constexpr long long O_PART   = O_RAWQ + (long long)B_ * LT_ * 4;
// end ~= 213 MB

extern "C" void kernel_launch(void* const* d_in, const int* in_sizes, int n_in,
                              void* d_out, int out_size, void* d_ws, size_t ws_size,
                              hipStream_t stream)
{
    const float* text  = (const float*)d_in[0];
    const float* image = (const float*)d_in[1];
    // d_in[2] = text_attention_mask (all ones; unused by the math)
    const float* w_b  = (const float*)d_in[3];
    const float* w_v  = (const float*)d_in[4];
    const float* w_q  = (const float*)d_in[5];
    const float* w_hv = (const float*)d_in[6];
    const float* w_hq = (const float*)d_in[7];
    const float* w_s  = (const float*)d_in[8];
    float* out = (float*)d_out;

    char* ws = (char*)d_ws;
    typedef unsigned short us;
    us* wq_qT_h = (us*)(ws + O_WQQT_H); us* wq_qT_l = (us*)(ws + O_WQQT_L);
    us* wv_vT_h = (us*)(ws + O_WVVT_H); us* wv_vT_l = (us*)(ws + O_WVVT_L);
    us* G_q_h   = (us*)(ws + O_GQ_H);   us* G_q_l   = (us*)(ws + O_GQ_L);
    us* M_q_h   = (us*)(ws + O_MQ_H);   us* M_q_l   = (us*)(ws + O_MQ_L);
    us* M_v_h   = (us*)(ws + O_MV_H);   us* M_v_l   = (us*)(ws + O_MV_L);
    us* P_v_h   = (us*)(ws + O_PV_H);   us* P_v_l   = (us*)(ws + O_PV_L);
    us* qqc_h   = (us*)(ws + O_QQC_H);  us* qqc_l   = (us*)(ws + O_QQC_L);
    us* vvc_h   = (us*)(ws + O_VVC_H);  us* vvc_l   = (us*)(ws + O_VVC_L);
    us* w_qT_h  = (us*)(ws + O_WQT_H);  us* w_qT_l  = (us*)(ws + O_WQT_L);
    us* w_vT_h  = (us*)(ws + O_WVT_H);  us* w_vT_l  = (us*)(ws + O_WVT_L);
    us* w_bT_h  = (us*)(ws + O_WBT_H);  us* w_bT_l  = (us*)(ws + O_WBT_L);
    us* w_bN_h  = (us*)(ws + O_WBN_H);  us* w_bN_l  = (us*)(ws + O_WBN_L);
    float* rawV = (float*)(ws + O_RAWV);
    float* rawQ = (float*)(ws + O_RAWQ);
    float* part = (float*)(ws + O_PART);

    const long long sTXT = (long long)LT_ * E_;   // fp32 elements
    const long long sIMG = (long long)LV_ * E_;
    const long long sT = (long long)K_ * LT_;     // plane elements
    const long long sV = (long long)K_ * LV_;
    const long long sKE = (long long)K_ * E_;

    // Weight prep (tiny)
    hipLaunchKernelGGL(wsplit_k, dim3(384), dim3(256), 0, stream, w_q, w_qT_h, w_qT_l, (us*)0, (us*)0, E_, K_);
    hipLaunchKernelGGL(wsplit_k, dim3(384), dim3(256), 0, stream, w_v, w_vT_h, w_vT_l, (us*)0, (us*)0, E_, K_);
    hipLaunchKernelGGL(wsplit_k, dim3(2304), dim3(256), 0, stream, w_b, w_bT_h, w_bT_l, w_bN_h, w_bN_l, E_, E_);

    // G1: wq_qT[b] = w_qT @ text[b]^T        C[128,1024], K=768
    hipLaunchKernelGGL((gemm128x64<SB_F32ROW>), dim3(16, B_), dim3(256), 0, stream,
                       w_qT_h, w_qT_l, text, nullptr, wq_qT_h, wq_qT_l,
                       LT_, E_, E_, 0LL, sTXT, sT);
    // G2: wv_vT[b] = w_vT @ image[b]^T       C[128,576], K=768
    hipLaunchKernelGGL((gemm128x64<SB_F32ROW>), dim3(9, B_), dim3(256), 0, stream,
                       w_vT_h, w_vT_l, image, nullptr, wv_vT_h, wv_vT_l,
                       LV_, E_, E_, 0LL, sIMG, sV);
    // G3: G_q[b] = wq_qT[b] @ text[b]        C[128,768], K=1024, B col-stored
    hipLaunchKernelGGL((gemm128x64<SB_F32COL>), dim3(12, B_), dim3(256), 0, stream,
                       wq_qT_h, wq_qT_l, text, nullptr, G_q_h, G_q_l,
                       E_, LT_, E_, sT, sTXT, sKE);
    // G4: M_q[b] = G_q[b] @ w_b              C[128,768], K=768, B' = w_bT planes
    hipLaunchKernelGGL((gemm128x64<SB_PLANE>), dim3(12, B_), dim3(256), 0, stream,
                       G_q_h, G_q_l, w_bT_h, w_bT_l, M_q_h, M_q_l,
                       E_, E_, E_, sKE, 0LL, sKE);
    // G5: wqqcT[b] = M_q[b] @ image[b]^T     C[128,576], K=768
    hipLaunchKernelGGL((gemm128x64<SB_F32ROW>), dim3(9, B_), dim3(256), 0, stream,
                       M_q_h, M_q_l, image, nullptr, qqc_h, qqc_l,
                       LV_, E_, E_, sKE, sIMG, sV);
    // G6: M_v[b] = wv_vT[b] @ image[b]       C[128,768], K=576, B col-stored
    hipLaunchKernelGGL((gemm128x64<SB_F32COL>), dim3(12, B_), dim3(256), 0, stream,
                       wv_vT_h, wv_vT_l, image, nullptr, M_v_h, M_v_l,
                       E_, LV_, E_, sV, sIMG, sKE);
    // G7: P_vT[b] = M_v[b] @ w_b^T           C[128,768], K=768, B' = w_b planes
    hipLaunchKernelGGL((gemm128x64<SB_PLANE>), dim3(12, B_), dim3(256), 0, stream,
                       M_v_h, M_v_l, w_bN_h, w_bN_l, P_v_h, P_v_l,
                       E_, E_, E_, sKE, 0LL, sKE);
    // G8: wvvcT[b] = P_vT[b] @ text[b]^T     C[128,1024], K=768
    hipLaunchKernelGGL((gemm128x64<SB_F32ROW>), dim3(16, B_), dim3(256), 0, stream,
                       P_v_h, P_v_l, text, nullptr, vvc_h, vvc_l,
                       LT_, E_, E_, sKE, sTXT, sT);

    // scores -> softmax -> contexts -> final
    hipLaunchKernelGGL(scores_part, dim3(B_, 2, 4), dim3(256), 0, stream,
                       wq_qT_h, wq_qT_l, vvc_h, vvc_l,
                       wv_vT_h, wv_vT_l, qqc_h, qqc_l,
                       w_hv, w_hq, rawV, rawQ);
    hipLaunchKernelGGL(softmax_k, dim3(B_, 2), dim3(256), 0, stream, rawV, rawQ);
    hipLaunchKernelGGL(context_k, dim3(B_, 2, 12), dim3(256), 0, stream,
                       text, image, rawQ, rawV, part);
    hipLaunchKernelGGL(final_k, dim3(3, B_), dim3(256), 0, stream,
                       part, w_s, out);
}